// Round 4
// baseline (601.714 us; speedup 1.0000x reference)
//
#include <hip/hip_runtime.h>
#include <hip/hip_bf16.h>

typedef unsigned short u16;
typedef unsigned int u32;
typedef __bf16 bf16_t;
typedef bf16_t bf16x8 __attribute__((ext_vector_type(8)));
typedef float fx4 __attribute__((ext_vector_type(4)));

#define TT 2048
#define HH 8
#define KK 64
#define VV 192
#define CC 1536

__device__ __forceinline__ float bf2f(u16 b) {
  union { u32 u; float f; } v; v.u = ((u32)b) << 16; return v.f;
}
__device__ __forceinline__ u16 f2bf(float f) {
  union { float f; u32 u; } v; v.f = f;
  return (u16)((v.u + 0x7FFFu + ((v.u >> 16) & 1u)) >> 16);
}
__device__ __forceinline__ fx4 mfma16(bf16x8 a, bf16x8 b, fx4 c) {
  return __builtin_amdgcn_mfma_f32_16x16x32_bf16(a, b, c, 0, 0, 0);
}

// ------------- tiled transpose, optional f32->bf16: out[c][r] = in[r][c] -----
// strides/offsets in ELEMENTS of the respective dtype.
template <bool IN_F32>
__global__ __launch_bounds__(256) void transpose_to_bf16(
    const void* __restrict__ in, u16* __restrict__ out,
    int in_rs, int out_rs, long in_bs, long out_bs) {
  __shared__ u16 tile[64][68];
  const int t = threadIdx.x;
  const int c0 = blockIdx.x * 64, r0 = blockIdx.y * 64;
  u16* outp = out + (size_t)blockIdx.z * out_bs;
  for (int i = 0; i < 4; ++i) {
    int idx = i * 256 + t;
    int r = idx >> 4, ch = idx & 15;
    size_t e = (size_t)blockIdx.z * in_bs + (size_t)(r0 + r) * in_rs + c0 + ch * 4;
    if (IN_F32) {
      float4 fv = *(const float4*)((const float*)in + e);
      tile[r][ch * 4 + 0] = f2bf(fv.x);
      tile[r][ch * 4 + 1] = f2bf(fv.y);
      tile[r][ch * 4 + 2] = f2bf(fv.z);
      tile[r][ch * 4 + 3] = f2bf(fv.w);
    } else {
      *(uint2*)&tile[r][ch * 4] = *(const uint2*)((const u16*)in + e);
    }
  }
  __syncthreads();
  for (int i = 0; i < 4; ++i) {
    int idx = i * 256 + t;
    int r = idx >> 4, ch = idx & 15;
    u16 a0 = tile[ch * 4 + 0][r], a1 = tile[ch * 4 + 1][r];
    u16 a2 = tile[ch * 4 + 2][r], a3 = tile[ch * 4 + 3][r];
    uint2 d;
    d.x = (u32)a0 | ((u32)a1 << 16);
    d.y = (u32)a2 | ((u32)a3 << 16);
    *(uint2*)&outp[(size_t)(c0 + r) * out_rs + r0 + ch * 4] = d;
  }
}

// ---------------- bf16 MFMA GEMM: C = A[M,K] @ BT[N,K]^T ---------------------
// A is f32 (AF32=true, converted at staging) or bf16. BT is bf16 (ws).
// EPI 0: qw[h][t][64]=acc/8+rwb(f32) ; qr=acc/8+rrb(f32)
// EPI 1: k [h][t][64]=acc
// EPI 2: out0 bf16 [m*N+n]=acc
// EPI 3: out0 FLOAT [m*N+n]=acc+bias0_f32[n]
template <int EPI, bool AF32>
__global__ __launch_bounds__(256) void gemm_bt(
    const void* __restrict__ A, const u16* __restrict__ BT,
    int M, int N, int Kd,
    void* __restrict__ out0, u16* __restrict__ out1,
    const float* __restrict__ bias0, const float* __restrict__ bias1) {
  __shared__ u16 As[128 * 32];
  __shared__ u16 Bs[128 * 32];
  const int t = threadIdx.x;
  const int lane = t & 63, wid = t >> 6;
  const int l16 = lane & 15, quad = lane >> 4;
  const int wm = wid >> 1, wn = wid & 1;
  const int m0 = blockIdx.y * 128, n0 = blockIdx.x * 128;

  fx4 acc[4][4] = {};
  for (int k0 = 0; k0 < Kd; k0 += 32) {
    __syncthreads();
    for (int i = 0; i < 2; ++i) {
      int idx = (i * 256 + t) * 8;
      int r = idx >> 5, ko = idx & 31;
      if (AF32) {
        const float* ap = (const float*)A + (size_t)(m0 + r) * Kd + k0 + ko;
        float4 f0 = *(const float4*)ap;
        float4 f1 = *(const float4*)(ap + 4);
        union { u16 h[8]; uint4 v; } pk;
        pk.h[0] = f2bf(f0.x); pk.h[1] = f2bf(f0.y);
        pk.h[2] = f2bf(f0.z); pk.h[3] = f2bf(f0.w);
        pk.h[4] = f2bf(f1.x); pk.h[5] = f2bf(f1.y);
        pk.h[6] = f2bf(f1.z); pk.h[7] = f2bf(f1.w);
        *(uint4*)&As[r * 32 + ko] = pk.v;
      } else {
        *(uint4*)&As[r * 32 + ko] =
            *(const uint4*)((const u16*)A + (size_t)(m0 + r) * Kd + k0 + ko);
      }
      *(uint4*)&Bs[r * 32 + ko] = *(const uint4*)&BT[(size_t)(n0 + r) * Kd + k0 + ko];
    }
    __syncthreads();
    bf16x8 af[4], bfr[4];
    for (int mi = 0; mi < 4; ++mi)
      af[mi] = *(const bf16x8*)&As[(wm * 64 + mi * 16 + l16) * 32 + quad * 8];
    for (int ni = 0; ni < 4; ++ni)
      bfr[ni] = *(const bf16x8*)&Bs[(wn * 64 + ni * 16 + l16) * 32 + quad * 8];
    for (int mi = 0; mi < 4; ++mi)
      for (int ni = 0; ni < 4; ++ni)
        acc[mi][ni] = mfma16(af[mi], bfr[ni], acc[mi][ni]);
  }

  for (int mi = 0; mi < 4; ++mi)
    for (int ni = 0; ni < 4; ++ni)
      for (int r = 0; r < 4; ++r) {
        int row = m0 + wm * 64 + mi * 16 + quad * 4 + r;
        int col = n0 + wn * 64 + ni * 16 + l16;
        float v = acc[mi][ni][r];
        if (EPI == 0) {
          float qs = v * 0.125f;
          int h = col >> 6, kx = col & 63;
          size_t o = ((size_t)h * TT + row) * 64 + kx;
          ((u16*)out0)[o] = f2bf(qs + bias0[col]);
          out1[o] = f2bf(qs + bias1[col]);
        } else if (EPI == 1) {
          int h = col >> 6, kx = col & 63;
          ((u16*)out0)[((size_t)h * TT + row) * 64 + kx] = f2bf(v);
        } else if (EPI == 2) {
          ((u16*)out0)[(size_t)row * N + col] = f2bf(v);
        } else {
          ((float*)out0)[(size_t)row * N + col] = v + bias0[col];
        }
      }
}

// ---------------- U/W suffix-sum tables for the rel-position term ------------
// u[h,q,i] = sum_k qr[h,q,k]*Wr_f32[i,h*64+k]; U[c]=suffix i>=c (first 16),
// W[c]=suffix over second 16.
__global__ __launch_bounds__(256) void uw_kernel(
    const u16* __restrict__ qr, const float* __restrict__ Wr,
    float* __restrict__ U, float* __restrict__ W) {
  const int h = blockIdx.y;
  const int t = threadIdx.x;
  const int ty = t >> 5, i = t & 31;
  const int q = blockIdx.x * 8 + ty;
  const u16* qp = qr + ((size_t)h * TT + q) * 64;
  const float* wp = Wr + (size_t)i * (HH * KK) + h * 64;
  float s = 0.0f;
  for (int kx = 0; kx < 64; ++kx) s += bf2f(qp[kx]) * wp[kx];
  __shared__ float u[8][33];
  u[ty][i] = s;
  __syncthreads();
  if (i < 16) {
    float su = 0.f, sw = 0.f;
    for (int j = i; j < 16; ++j) { su += u[ty][j]; sw += u[ty][16 + j]; }
    U[((size_t)h * TT + q) * 16 + i] = su;
    W[((size_t)h * TT + q) * 16 + i] = sw;
  }
}

// ---------------- fused flash attention with table-based rel term ------------
// block = 256 (4 waves), each wave owns 16 q-rows; grid (T/64, H)
__global__ __launch_bounds__(256) void attn_kernel(
    const u16* __restrict__ qw, const u16* __restrict__ Kw,
    const u16* __restrict__ vT, const float* __restrict__ Ug,
    const float* __restrict__ Wg, u16* __restrict__ aout) {
  const int h = blockIdx.y;
  const int q0 = blockIdx.x * 64;
  const int t = threadIdx.x;
  const int lane = t & 63, w = t >> 6;
  const int l16 = lane & 15, quad = lane >> 4;

  __shared__ unsigned char cidx[TT];
  __shared__ float Ul[64][17];
  __shared__ float Wl[64][17];
  __shared__ u16 Pl[4][16 * 72];   // stride 72 to spread LDS banks

  {
    // borzoi center widths: cw[i] = pow_rate^(i+1) - 1, pow_rate = (T+1)^(1/16)
    float pr = expf(logf((float)(TT + 1)) / 16.0f);
    float cw[16];
    float wv = pr;
    for (int i = 0; i < 16; ++i) { cw[i] = wv - 1.0f; wv *= pr; }
    for (int idx = t; idx < TT; idx += 256) {
      int c = 15;
      for (int i = 14; i >= 0; --i)
        if (cw[i] > (float)idx) c = i;
      cidx[idx] = (unsigned char)c;
    }
  }
  for (int i = t; i < 64 * 16; i += 256) {
    int ql = i >> 4, c = i & 15;
    Ul[ql][c] = Ug[((size_t)h * TT + q0 + ql) * 16 + c];
    Wl[ql][c] = Wg[((size_t)h * TT + q0 + ql) * 16 + c];
  }
  __syncthreads();

  const u16* qp = qw + ((size_t)h * TT + q0 + w * 16 + l16) * 64 + quad * 8;
  const bf16x8 aq0 = *(const bf16x8*)qp;
  const bf16x8 aq1 = *(const bf16x8*)(qp + 32);

  float m_r[4], l_r[4];
  for (int r = 0; r < 4; ++r) { m_r[r] = -3.0e38f; l_r[r] = 0.0f; }
  fx4 o[12] = {};

  const u16* kbase = Kw + (size_t)h * TT * 64;
  const u16* vbase = vT + (size_t)h * VV * TT;
  const int qrl = w * 16 + quad * 4;

  for (int j0 = 0; j0 < TT; j0 += 64) {
    fx4 s[4] = {};
    for (int jt = 0; jt < 4; ++jt) {
      const u16* kp = kbase + (size_t)(j0 + jt * 16 + l16) * 64 + quad * 8;
      s[jt] = mfma16(aq0, *(const bf16x8*)kp, s[jt]);
      s[jt] = mfma16(aq1, *(const bf16x8*)(kp + 32), s[jt]);
    }
    // add relative-position logits via table lookup
    for (int jt = 0; jt < 4; ++jt) {
      int j = j0 + jt * 16 + l16;
      for (int r = 0; r < 4; ++r) {
        int d = j - (q0 + qrl + r);
        int ad = d < 0 ? -d : d;
        int c = cidx[ad];
        float wv = Wl[qrl + r][c];
        s[jt][r] += Ul[qrl + r][c] + (d > 0 ? wv : (d < 0 ? -wv : 0.0f));
      }
    }
    // online softmax (rows live in the 16 lanes sharing this quad)
    float p[4][4];
    for (int r = 0; r < 4; ++r) {
      float mx = fmaxf(fmaxf(s[0][r], s[1][r]), fmaxf(s[2][r], s[3][r]));
      for (int msk = 1; msk < 16; msk <<= 1) mx = fmaxf(mx, __shfl_xor(mx, msk, 64));
      float mnew = fmaxf(m_r[r], mx);
      float alpha = __expf(m_r[r] - mnew);
      float ps = 0.0f;
      for (int jt = 0; jt < 4; ++jt) { p[jt][r] = __expf(s[jt][r] - mnew); ps += p[jt][r]; }
      for (int msk = 1; msk < 16; msk <<= 1) ps += __shfl_xor(ps, msk, 64);
      l_r[r] = l_r[r] * alpha + ps;
      m_r[r] = mnew;
      for (int vt = 0; vt < 12; ++vt) o[vt][r] *= alpha;
    }
    // P: C-layout -> LDS -> A-layout for PV
    __syncthreads();
    for (int jt = 0; jt < 4; ++jt)
      for (int r = 0; r < 4; ++r)
        Pl[w][(quad * 4 + r) * 72 + jt * 16 + l16] = f2bf(p[jt][r]);
    __syncthreads();
    for (int ks = 0; ks < 2; ++ks) {
      bf16x8 pf = *(const bf16x8*)&Pl[w][l16 * 72 + ks * 32 + quad * 8];
      const u16* vp = vbase + (size_t)l16 * TT + j0 + ks * 32 + quad * 8;
      for (int vt = 0; vt < 12; ++vt) {
        bf16x8 bv = *(const bf16x8*)(vp + (size_t)vt * 16 * TT);
        o[vt] = mfma16(pf, bv, o[vt]);
      }
    }
  }
  for (int r = 0; r < 4; ++r) {
    float inv = 1.0f / l_r[r];
    int row = q0 + qrl + r;
    u16* op = aout + (size_t)row * CC + h * VV + l16;
    for (int vt = 0; vt < 12; ++vt) op[vt * 16] = f2bf(o[vt][r] * inv);
  }
}

extern "C" void kernel_launch(void* const* d_in, const int* in_sizes, int n_in,
                              void* d_out, int out_size, void* d_ws, size_t ws_size,
                              hipStream_t stream) {
  (void)in_sizes; (void)n_in; (void)out_size; (void)ws_size;
  // ALL inputs f32 (reference dtypes); output f32.
  const void*  x   = d_in[0];             // [2048, 1536] f32
  const void*  Wq  = d_in[1];             // [1536, 512]  f32
  const void*  Wk  = d_in[2];             // [1536, 512]  f32
  const void*  Wv  = d_in[3];             // [1536, 1536] f32
  const float* Wr  = (const float*)d_in[4];   // [32, 512]
  const float* rwb = (const float*)d_in[5];   // [512]
  const float* rrb = (const float*)d_in[6];   // [512]
  const void*  Wo  = d_in[7];             // [1536, 1536] f32
  const float* bo  = (const float*)d_in[8];   // [1536]

  char* ws = (char*)d_ws;
  size_t off = 0;
  auto alloc = [&](size_t bytes) -> void* {
    void* p = ws + off;
    off += (bytes + 255) & ~(size_t)255;
    return p;
  };
  u16* WqT  = (u16*)alloc((size_t)512 * 1536 * 2);
  u16* WkT  = (u16*)alloc((size_t)512 * 1536 * 2);
  u16* WvT  = (u16*)alloc((size_t)1536 * 1536 * 2);
  u16* WoT  = (u16*)alloc((size_t)1536 * 1536 * 2);
  u16* qw   = (u16*)alloc((size_t)HH * TT * 64 * 2);
  u16* qr   = (u16*)alloc((size_t)HH * TT * 64 * 2);
  u16* Kws  = (u16*)alloc((size_t)HH * TT * 64 * 2);
  u16* vtmp = (u16*)alloc((size_t)TT * CC * 2);
  u16* vTw  = (u16*)alloc((size_t)HH * VV * TT * 2);
  float* Uw = (float*)alloc((size_t)HH * TT * 16 * 4);
  float* Ww = (float*)alloc((size_t)HH * TT * 16 * 4);
  u16* aout = (u16*)alloc((size_t)TT * CC * 2);

  // weight transposes: f32 [K,N] -> bf16 [N,K]
  transpose_to_bf16<true><<<dim3(8, 24, 1), 256, 0, stream>>>(Wq, WqT, 512, 1536, 0, 0);
  transpose_to_bf16<true><<<dim3(8, 24, 1), 256, 0, stream>>>(Wk, WkT, 512, 1536, 0, 0);
  transpose_to_bf16<true><<<dim3(24, 24, 1), 256, 0, stream>>>(Wv, WvT, 1536, 1536, 0, 0);
  transpose_to_bf16<true><<<dim3(24, 24, 1), 256, 0, stream>>>(Wo, WoT, 1536, 1536, 0, 0);

  // projections (A = x f32, converted at staging)
  gemm_bt<0, true><<<dim3(4, 16), 256, 0, stream>>>(x, WqT, TT, 512, CC, qw, qr, rwb, rrb);
  gemm_bt<1, true><<<dim3(4, 16), 256, 0, stream>>>(x, WkT, TT, 512, CC, Kws, nullptr, nullptr, nullptr);
  gemm_bt<2, true><<<dim3(12, 16), 256, 0, stream>>>(x, WvT, TT, CC, CC, vtmp, nullptr, nullptr, nullptr);

  // v -> per-head transposed [h][vv][t] (bf16 -> bf16)
  transpose_to_bf16<false><<<dim3(3, 32, 8), 256, 0, stream>>>(vtmp, vTw, 1536, 2048, 192, (long)192 * 2048);

  // rel-position suffix tables
  uw_kernel<<<dim3(256, 8), 256, 0, stream>>>(qr, Wr, Uw, Ww);

  // fused attention
  attn_kernel<<<dim3(32, 8), 256, 0, stream>>>(qw, Kws, vTw, Uw, Ww, aout);

  // output projection: bf16 aout @ WoT + bo -> FLOAT d_out
  gemm_bt<3, false><<<dim3(12, 16), 256, 0, stream>>>(aout, WoT, TT, CC, CC, d_out, nullptr, bo, nullptr);
}

// Round 5
// 500.046 us; speedup vs baseline: 1.2033x; 1.2033x over previous
//
#include <hip/hip_runtime.h>
#include <hip/hip_bf16.h>

typedef unsigned short u16;
typedef unsigned int u32;
typedef __bf16 bf16_t;
typedef bf16_t bf16x8 __attribute__((ext_vector_type(8)));
typedef float fx4 __attribute__((ext_vector_type(4)));

#define TT 2048
#define HH 8
#define KK 64
#define VV 192
#define CC 1536
#define SPLITS 4
#define JBLK (TT / SPLITS)

__device__ __forceinline__ float bf2f(u16 b) {
  union { u32 u; float f; } v; v.u = ((u32)b) << 16; return v.f;
}
__device__ __forceinline__ u16 f2bf(float f) {
  union { float f; u32 u; } v; v.f = f;
  return (u16)((v.u + 0x7FFFu + ((v.u >> 16) & 1u)) >> 16);
}
__device__ __forceinline__ fx4 mfma16(bf16x8 a, bf16x8 b, fx4 c) {
  return __builtin_amdgcn_mfma_f32_16x16x32_bf16(a, b, c, 0, 0, 0);
}

// ------------- tiled transpose, optional f32->bf16: out[c][r] = in[r][c] -----
template <bool IN_F32>
__global__ __launch_bounds__(256) void transpose_to_bf16(
    const void* __restrict__ in, u16* __restrict__ out,
    int in_rs, int out_rs, long in_bs, long out_bs) {
  __shared__ u16 tile[64][68];
  const int t = threadIdx.x;
  const int c0 = blockIdx.x * 64, r0 = blockIdx.y * 64;
  u16* outp = out + (size_t)blockIdx.z * out_bs;
  for (int i = 0; i < 4; ++i) {
    int idx = i * 256 + t;
    int r = idx >> 4, ch = idx & 15;
    size_t e = (size_t)blockIdx.z * in_bs + (size_t)(r0 + r) * in_rs + c0 + ch * 4;
    if (IN_F32) {
      float4 fv = *(const float4*)((const float*)in + e);
      tile[r][ch * 4 + 0] = f2bf(fv.x);
      tile[r][ch * 4 + 1] = f2bf(fv.y);
      tile[r][ch * 4 + 2] = f2bf(fv.z);
      tile[r][ch * 4 + 3] = f2bf(fv.w);
    } else {
      *(uint2*)&tile[r][ch * 4] = *(const uint2*)((const u16*)in + e);
    }
  }
  __syncthreads();
  for (int i = 0; i < 4; ++i) {
    int idx = i * 256 + t;
    int r = idx >> 4, ch = idx & 15;
    u16 a0 = tile[ch * 4 + 0][r], a1 = tile[ch * 4 + 1][r];
    u16 a2 = tile[ch * 4 + 2][r], a3 = tile[ch * 4 + 3][r];
    uint2 d;
    d.x = (u32)a0 | ((u32)a1 << 16);
    d.y = (u32)a2 | ((u32)a3 << 16);
    *(uint2*)&outp[(size_t)(c0 + r) * out_rs + r0 + ch * 4] = d;
  }
}

// ---------------- bf16 MFMA GEMM: C = A[M,K] @ BT[N,K]^T ---------------------
// EPI 0: qw[h][t][64]=acc/8+rwb(f32) ; qr=acc/8+rrb(f32)
// EPI 1: k [h][t][64]=acc
// EPI 2: out0 bf16 [m*N+n]=acc
// EPI 3: out0 FLOAT [m*N+n]=acc+bias0_f32[n]
template <int EPI, bool AF32>
__global__ __launch_bounds__(256) void gemm_bt(
    const void* __restrict__ A, const u16* __restrict__ BT,
    int M, int N, int Kd,
    void* __restrict__ out0, u16* __restrict__ out1,
    const float* __restrict__ bias0, const float* __restrict__ bias1) {
  __shared__ u16 As[128 * 32];
  __shared__ u16 Bs[128 * 32];
  const int t = threadIdx.x;
  const int lane = t & 63, wid = t >> 6;
  const int l16 = lane & 15, quad = lane >> 4;
  const int wm = wid >> 1, wn = wid & 1;
  const int m0 = blockIdx.y * 128, n0 = blockIdx.x * 128;

  fx4 acc[4][4] = {};
  for (int k0 = 0; k0 < Kd; k0 += 32) {
    __syncthreads();
    for (int i = 0; i < 2; ++i) {
      int idx = (i * 256 + t) * 8;
      int r = idx >> 5, ko = idx & 31;
      if (AF32) {
        const float* ap = (const float*)A + (size_t)(m0 + r) * Kd + k0 + ko;
        float4 f0 = *(const float4*)ap;
        float4 f1 = *(const float4*)(ap + 4);
        union { u16 h[8]; uint4 v; } pk;
        pk.h[0] = f2bf(f0.x); pk.h[1] = f2bf(f0.y);
        pk.h[2] = f2bf(f0.z); pk.h[3] = f2bf(f0.w);
        pk.h[4] = f2bf(f1.x); pk.h[5] = f2bf(f1.y);
        pk.h[6] = f2bf(f1.z); pk.h[7] = f2bf(f1.w);
        *(uint4*)&As[r * 32 + ko] = pk.v;
      } else {
        *(uint4*)&As[r * 32 + ko] =
            *(const uint4*)((const u16*)A + (size_t)(m0 + r) * Kd + k0 + ko);
      }
      *(uint4*)&Bs[r * 32 + ko] = *(const uint4*)&BT[(size_t)(n0 + r) * Kd + k0 + ko];
    }
    __syncthreads();
    bf16x8 af[4], bfr[4];
    for (int mi = 0; mi < 4; ++mi)
      af[mi] = *(const bf16x8*)&As[(wm * 64 + mi * 16 + l16) * 32 + quad * 8];
    for (int ni = 0; ni < 4; ++ni)
      bfr[ni] = *(const bf16x8*)&Bs[(wn * 64 + ni * 16 + l16) * 32 + quad * 8];
    for (int mi = 0; mi < 4; ++mi)
      for (int ni = 0; ni < 4; ++ni)
        acc[mi][ni] = mfma16(af[mi], bfr[ni], acc[mi][ni]);
  }

  for (int mi = 0; mi < 4; ++mi)
    for (int ni = 0; ni < 4; ++ni)
      for (int r = 0; r < 4; ++r) {
        int row = m0 + wm * 64 + mi * 16 + quad * 4 + r;
        int col = n0 + wn * 64 + ni * 16 + l16;
        float v = acc[mi][ni][r];
        if (EPI == 0) {
          float qs = v * 0.125f;
          int h = col >> 6, kx = col & 63;
          size_t o = ((size_t)h * TT + row) * 64 + kx;
          ((u16*)out0)[o] = f2bf(qs + bias0[col]);
          out1[o] = f2bf(qs + bias1[col]);
        } else if (EPI == 1) {
          int h = col >> 6, kx = col & 63;
          ((u16*)out0)[((size_t)h * TT + row) * 64 + kx] = f2bf(v);
        } else if (EPI == 2) {
          ((u16*)out0)[(size_t)row * N + col] = f2bf(v);
        } else {
          ((float*)out0)[(size_t)row * N + col] = v + bias0[col];
        }
      }
}

// ---------------- global cidx table: category of |distance| ------------------
__global__ __launch_bounds__(256) void cidx_kernel(unsigned char* __restrict__ cidx_g) {
  float pr = expf(logf((float)(TT + 1)) / 16.0f);
  float cw[16];
  float wv = pr;
  for (int i = 0; i < 16; ++i) { cw[i] = wv - 1.0f; wv *= pr; }
  for (int idx = threadIdx.x; idx < TT; idx += 256) {
    int c = 15;
    for (int i = 14; i >= 0; --i)
      if (cw[i] > (float)idx) c = i;
    cidx_g[idx] = (unsigned char)c;
  }
}

// ---------------- U/W suffix-sum tables for the rel-position term ------------
__global__ __launch_bounds__(256) void uw_kernel(
    const u16* __restrict__ qr, const float* __restrict__ Wr,
    float* __restrict__ U, float* __restrict__ W) {
  const int h = blockIdx.y;
  const int t = threadIdx.x;
  const int ty = t >> 5, i = t & 31;
  const int q = blockIdx.x * 8 + ty;
  const u16* qp = qr + ((size_t)h * TT + q) * 64;
  const float* wp = Wr + (size_t)i * (HH * KK) + h * 64;
  float s = 0.0f;
  for (int kx = 0; kx < 64; ++kx) s += bf2f(qp[kx]) * wp[kx];
  __shared__ float u[8][33];
  u[ty][i] = s;
  __syncthreads();
  if (i < 16) {
    float su = 0.f, sw = 0.f;
    for (int j = i; j < 16; ++j) { su += u[ty][j]; sw += u[ty][16 + j]; }
    U[((size_t)h * TT + q) * 16 + i] = su;
    W[((size_t)h * TT + q) * 16 + i] = sw;
  }
}

// ---------------- split-K fused flash attention ------------------------------
// grid (T/64, H, SPLITS); block 256 (4 waves, 16 q-rows each).
// Writes unnormalized o partials + per-row (m, l) for the combine pass.
__global__ __launch_bounds__(256) void attn_split(
    const u16* __restrict__ qw, const u16* __restrict__ Kw,
    const u16* __restrict__ vT, const float* __restrict__ Ug,
    const float* __restrict__ Wg, const unsigned char* __restrict__ cidx_g,
    float* __restrict__ o_part, float* __restrict__ m_part,
    float* __restrict__ l_part) {
  const int h = blockIdx.y;
  const int q0 = blockIdx.x * 64;
  const int ks = blockIdx.z;
  const int t = threadIdx.x;
  const int lane = t & 63, w = t >> 6;
  const int l16 = lane & 15, quad = lane >> 4;

  __shared__ unsigned char cidx[TT];
  __shared__ float Ul[64][17];
  __shared__ float Wl[64][17];
  __shared__ u16 Pl[4][16 * 72];

  *(uint2*)&cidx[t * 8] = *(const uint2*)&cidx_g[t * 8];
  for (int i = t; i < 64 * 16; i += 256) {
    int ql = i >> 4, c = i & 15;
    Ul[ql][c] = Ug[((size_t)h * TT + q0 + ql) * 16 + c];
    Wl[ql][c] = Wg[((size_t)h * TT + q0 + ql) * 16 + c];
  }
  __syncthreads();

  const u16* qp = qw + ((size_t)h * TT + q0 + w * 16 + l16) * 64 + quad * 8;
  const bf16x8 aq0 = *(const bf16x8*)qp;
  const bf16x8 aq1 = *(const bf16x8*)(qp + 32);

  float m_r[4], l_r[4];
  for (int r = 0; r < 4; ++r) { m_r[r] = -3.0e38f; l_r[r] = 0.0f; }
  fx4 o[12] = {};

  const u16* kbase = Kw + (size_t)h * TT * 64;
  const u16* vbase = vT + (size_t)h * VV * TT;
  const int qrl = w * 16 + quad * 4;

  for (int j0 = ks * JBLK; j0 < (ks + 1) * JBLK; j0 += 64) {
    fx4 s[4] = {};
    for (int jt = 0; jt < 4; ++jt) {
      const u16* kp = kbase + (size_t)(j0 + jt * 16 + l16) * 64 + quad * 8;
      s[jt] = mfma16(aq0, *(const bf16x8*)kp, s[jt]);
      s[jt] = mfma16(aq1, *(const bf16x8*)(kp + 32), s[jt]);
    }
    // relative-position logits via table lookup
    for (int jt = 0; jt < 4; ++jt) {
      int j = j0 + jt * 16 + l16;
      for (int r = 0; r < 4; ++r) {
        int d = j - (q0 + qrl + r);
        int ad = d < 0 ? -d : d;
        int c = cidx[ad];
        float wv = Wl[qrl + r][c];
        s[jt][r] += Ul[qrl + r][c] + (d > 0 ? wv : (d < 0 ? -wv : 0.0f));
      }
    }
    // online softmax across the quad's 16 lanes (keys)
    float p[4][4];
    for (int r = 0; r < 4; ++r) {
      float mx = fmaxf(fmaxf(s[0][r], s[1][r]), fmaxf(s[2][r], s[3][r]));
      for (int msk = 1; msk < 16; msk <<= 1) mx = fmaxf(mx, __shfl_xor(mx, msk, 64));
      float mnew = fmaxf(m_r[r], mx);
      float alpha = __expf(m_r[r] - mnew);
      float ps = 0.0f;
      for (int jt = 0; jt < 4; ++jt) { p[jt][r] = __expf(s[jt][r] - mnew); ps += p[jt][r]; }
      for (int msk = 1; msk < 16; msk <<= 1) ps += __shfl_xor(ps, msk, 64);
      l_r[r] = l_r[r] * alpha + ps;
      m_r[r] = mnew;
      for (int vt = 0; vt < 12; ++vt) o[vt][r] *= alpha;
    }
    // P: C-layout -> LDS -> A-layout. Pl[w] is wave-private: no block barrier,
    // just drain this wave's own LDS ops (lockstep wave64 => all lanes' writes
    // are issued before the waitcnt).
    asm volatile("s_waitcnt lgkmcnt(0)" ::: "memory");
    for (int jt = 0; jt < 4; ++jt)
      for (int r = 0; r < 4; ++r)
        Pl[w][(quad * 4 + r) * 72 + jt * 16 + l16] = f2bf(p[jt][r]);
    asm volatile("s_waitcnt lgkmcnt(0)" ::: "memory");
    for (int kss = 0; kss < 2; ++kss) {
      bf16x8 pf = *(const bf16x8*)&Pl[w][l16 * 72 + kss * 32 + quad * 8];
      const u16* vp = vbase + (size_t)l16 * TT + j0 + kss * 32 + quad * 8;
      for (int vt = 0; vt < 12; ++vt) {
        bf16x8 bv = *(const bf16x8*)(vp + (size_t)vt * 16 * TT);
        o[vt] = mfma16(pf, bv, o[vt]);
      }
    }
  }
  // write unnormalized partials
  for (int r = 0; r < 4; ++r) {
    int row = q0 + qrl + r;
    size_t base = ((size_t)(ks * HH + h) * TT + row) * VV;
    for (int vt = 0; vt < 12; ++vt) o_part[base + vt * 16 + l16] = o[vt][r];
    if (l16 == 0) {
      m_part[(size_t)(ks * HH + h) * TT + row] = m_r[r];
      l_part[(size_t)(ks * HH + h) * TT + row] = l_r[r];
    }
  }
}

// ---------------- combine split-K partials -> bf16 aout ----------------------
// grid (T/16, H); block 256 = 16 rows x 16 col-threads (12 channels each)
__global__ __launch_bounds__(256) void attn_combine(
    const float* __restrict__ o_part, const float* __restrict__ m_part,
    const float* __restrict__ l_part, u16* __restrict__ aout) {
  const int h = blockIdx.y;
  const int row = blockIdx.x * 16 + (threadIdx.x >> 4);
  const int c0 = (threadIdx.x & 15) * 12;

  float m[SPLITS], M = -3.0e38f;
  for (int s = 0; s < SPLITS; ++s) {
    m[s] = m_part[(size_t)(s * HH + h) * TT + row];
    M = fmaxf(M, m[s]);
  }
  float lsum = 0.0f, wgt[SPLITS];
  for (int s = 0; s < SPLITS; ++s) {
    wgt[s] = __expf(m[s] - M);
    lsum += wgt[s] * l_part[(size_t)(s * HH + h) * TT + row];
  }
  float o[12];
  for (int j = 0; j < 12; ++j) o[j] = 0.0f;
  for (int s = 0; s < SPLITS; ++s) {
    const float* op = o_part + ((size_t)(s * HH + h) * TT + row) * VV + c0;
    float ws = wgt[s];
    for (int j = 0; j < 12; j += 4) {
      float4 v = *(const float4*)&op[j];
      o[j + 0] = fmaf(ws, v.x, o[j + 0]);
      o[j + 1] = fmaf(ws, v.y, o[j + 1]);
      o[j + 2] = fmaf(ws, v.z, o[j + 2]);
      o[j + 3] = fmaf(ws, v.w, o[j + 3]);
    }
  }
  float inv = 1.0f / lsum;
  union { u16 hx[12]; uint2 v2[3]; } pk;
  for (int j = 0; j < 12; ++j) pk.hx[j] = f2bf(o[j] * inv);
  u16* dst = aout + (size_t)row * CC + h * VV + c0;
  *(uint2*)&dst[0] = pk.v2[0];
  *(uint2*)&dst[4] = pk.v2[1];
  *(uint2*)&dst[8] = pk.v2[2];
}

extern "C" void kernel_launch(void* const* d_in, const int* in_sizes, int n_in,
                              void* d_out, int out_size, void* d_ws, size_t ws_size,
                              hipStream_t stream) {
  (void)in_sizes; (void)n_in; (void)out_size; (void)ws_size;
  const void*  x   = d_in[0];               // [2048, 1536] f32
  const void*  Wq  = d_in[1];               // [1536, 512]  f32
  const void*  Wk  = d_in[2];               // [1536, 512]  f32
  const void*  Wv  = d_in[3];               // [1536, 1536] f32
  const float* Wr  = (const float*)d_in[4]; // [32, 512]
  const float* rwb = (const float*)d_in[5]; // [512]
  const float* rrb = (const float*)d_in[6]; // [512]
  const void*  Wo  = d_in[7];               // [1536, 1536] f32
  const float* bo  = (const float*)d_in[8]; // [1536]

  char* ws = (char*)d_ws;
  size_t off = 0;
  auto alloc = [&](size_t bytes) -> void* {
    void* p = ws + off;
    off += (bytes + 255) & ~(size_t)255;
    return p;
  };
  u16* WqT  = (u16*)alloc((size_t)512 * 1536 * 2);
  u16* WkT  = (u16*)alloc((size_t)512 * 1536 * 2);
  u16* WvT  = (u16*)alloc((size_t)1536 * 1536 * 2);
  u16* WoT  = (u16*)alloc((size_t)1536 * 1536 * 2);
  u16* qw   = (u16*)alloc((size_t)HH * TT * 64 * 2);
  u16* qr   = (u16*)alloc((size_t)HH * TT * 64 * 2);
  u16* Kws  = (u16*)alloc((size_t)HH * TT * 64 * 2);
  u16* vtmp = (u16*)alloc((size_t)TT * CC * 2);
  u16* vTw  = (u16*)alloc((size_t)HH * VV * TT * 2);
  float* Uw = (float*)alloc((size_t)HH * TT * 16 * 4);
  float* Ww = (float*)alloc((size_t)HH * TT * 16 * 4);
  u16* aout = (u16*)alloc((size_t)TT * CC * 2);
  unsigned char* cidx_g = (unsigned char*)alloc(TT);
  float* o_part = (float*)alloc((size_t)SPLITS * HH * TT * VV * 4);
  float* m_part = (float*)alloc((size_t)SPLITS * HH * TT * 4);
  float* l_part = (float*)alloc((size_t)SPLITS * HH * TT * 4);

  // weight transposes: f32 [K,N] -> bf16 [N,K]
  transpose_to_bf16<true><<<dim3(8, 24, 1), 256, 0, stream>>>(Wq, WqT, 512, 1536, 0, 0);
  transpose_to_bf16<true><<<dim3(8, 24, 1), 256, 0, stream>>>(Wk, WkT, 512, 1536, 0, 0);
  transpose_to_bf16<true><<<dim3(24, 24, 1), 256, 0, stream>>>(Wv, WvT, 1536, 1536, 0, 0);
  transpose_to_bf16<true><<<dim3(24, 24, 1), 256, 0, stream>>>(Wo, WoT, 1536, 1536, 0, 0);
  cidx_kernel<<<1, 256, 0, stream>>>(cidx_g);

  // projections (A = x f32, converted at staging)
  gemm_bt<0, true><<<dim3(4, 16), 256, 0, stream>>>(x, WqT, TT, 512, CC, qw, qr, rwb, rrb);
  gemm_bt<1, true><<<dim3(4, 16), 256, 0, stream>>>(x, WkT, TT, 512, CC, Kws, nullptr, nullptr, nullptr);
  gemm_bt<2, true><<<dim3(12, 16), 256, 0, stream>>>(x, WvT, TT, CC, CC, vtmp, nullptr, nullptr, nullptr);

  // v -> per-head transposed [h][vv][t] (bf16 -> bf16)
  transpose_to_bf16<false><<<dim3(3, 32, 8), 256, 0, stream>>>(vtmp, vTw, 1536, 2048, 192, (long)192 * 2048);

  // rel-position suffix tables
  uw_kernel<<<dim3(256, 8), 256, 0, stream>>>(qr, Wr, Uw, Ww);

  // split-K fused attention + combine
  attn_split<<<dim3(32, 8, SPLITS), 256, 0, stream>>>(qw, Kws, vTw, Uw, Ww, cidx_g,
                                                      o_part, m_part, l_part);
  attn_combine<<<dim3(128, 8), 256, 0, stream>>>(o_part, m_part, l_part, aout);

  // output projection: bf16 aout @ WoT + bo -> FLOAT d_out
  gemm_bt<3, false><<<dim3(12, 16), 256, 0, stream>>>(aout, WoT, TT, CC, CC, d_out, nullptr, bo, nullptr);
}

// Round 6
// 428.232 us; speedup vs baseline: 1.4051x; 1.1677x over previous
//
#include <hip/hip_runtime.h>
#include <hip/hip_bf16.h>

typedef unsigned short u16;
typedef unsigned int u32;
typedef __bf16 bf16_t;
typedef bf16_t bf16x8 __attribute__((ext_vector_type(8)));
typedef float fx4 __attribute__((ext_vector_type(4)));

#define TT 2048
#define HH 8
#define KK 64
#define VV 192
#define CC 1536
#define SPLITS 8
#define JBLK (TT / SPLITS)

__device__ __forceinline__ float bf2f(u16 b) {
  union { u32 u; float f; } v; v.u = ((u32)b) << 16; return v.f;
}
__device__ __forceinline__ u16 f2bf(float f) {
  union { float f; u32 u; } v; v.f = f;
  return (u16)((v.u + 0x7FFFu + ((v.u >> 16) & 1u)) >> 16);
}
__device__ __forceinline__ fx4 mfma16(bf16x8 a, bf16x8 b, fx4 c) {
  return __builtin_amdgcn_mfma_f32_16x16x32_bf16(a, b, c, 0, 0, 0);
}

// ---------------- prep: all 4 weight transposes (f32->bf16) + cidx table -----
// z=0: Wq[1536,512]->WqT[512,1536]   z=1: Wk likewise
// z=2: Wv[1536,1536]->WvT            z=3: Wo likewise
// z=4: (block 0,0 only) borzoi |distance| -> category table
__global__ __launch_bounds__(256) void prep_kernel(
    const float* __restrict__ Wq, const float* __restrict__ Wk,
    const float* __restrict__ Wv, const float* __restrict__ Wo,
    u16* __restrict__ WqT, u16* __restrict__ WkT,
    u16* __restrict__ WvT, u16* __restrict__ WoT,
    unsigned char* __restrict__ cidx_g) {
  const int z = blockIdx.z;
  const int t = threadIdx.x;
  if (z == 4) {
    if (blockIdx.x != 0 || blockIdx.y != 0) return;
    float pr = expf(logf((float)(TT + 1)) / 16.0f);
    float cw[16];
    float wv = pr;
    for (int i = 0; i < 16; ++i) { cw[i] = wv - 1.0f; wv *= pr; }
    for (int idx = t; idx < TT; idx += 256) {
      int c = 15;
      for (int i = 14; i >= 0; --i)
        if (cw[i] > (float)idx) c = i;
      cidx_g[idx] = (unsigned char)c;
    }
    return;
  }
  if (z < 2 && blockIdx.x >= 8) return;
  const float* in = (z == 0) ? Wq : (z == 1) ? Wk : (z == 2) ? Wv : Wo;
  u16* out = (z == 0) ? WqT : (z == 1) ? WkT : (z == 2) ? WvT : WoT;
  const int in_rs = (z < 2) ? 512 : 1536;
  const int out_rs = 1536;

  __shared__ u16 tile[64][68];
  const int c0 = blockIdx.x * 64, r0 = blockIdx.y * 64;
  for (int i = 0; i < 4; ++i) {
    int idx = i * 256 + t;
    int r = idx >> 4, ch = idx & 15;
    float4 fv = *(const float4*)&in[(size_t)(r0 + r) * in_rs + c0 + ch * 4];
    tile[r][ch * 4 + 0] = f2bf(fv.x);
    tile[r][ch * 4 + 1] = f2bf(fv.y);
    tile[r][ch * 4 + 2] = f2bf(fv.z);
    tile[r][ch * 4 + 3] = f2bf(fv.w);
  }
  __syncthreads();
  for (int i = 0; i < 4; ++i) {
    int idx = i * 256 + t;
    int r = idx >> 4, ch = idx & 15;
    u16 a0 = tile[ch * 4 + 0][r], a1 = tile[ch * 4 + 1][r];
    u16 a2 = tile[ch * 4 + 2][r], a3 = tile[ch * 4 + 3][r];
    uint2 d;
    d.x = (u32)a0 | ((u32)a1 << 16);
    d.y = (u32)a2 | ((u32)a3 << 16);
    *(uint2*)&out[(size_t)(c0 + r) * out_rs + r0 + ch * 4] = d;
  }
}

// ---------------- bf16 transpose for v: out[c][r] = in[r][c] -----------------
__global__ __launch_bounds__(256) void transpose_bf16(
    const u16* __restrict__ in, u16* __restrict__ out,
    int in_rs, int out_rs, long in_bs, long out_bs) {
  __shared__ u16 tile[64][68];
  const int t = threadIdx.x;
  const int c0 = blockIdx.x * 64, r0 = blockIdx.y * 64;
  const u16* inp = in + (size_t)blockIdx.z * in_bs;
  u16* outp = out + (size_t)blockIdx.z * out_bs;
  for (int i = 0; i < 4; ++i) {
    int idx = i * 256 + t;
    int r = idx >> 4, ch = idx & 15;
    *(uint2*)&tile[r][ch * 4] =
        *(const uint2*)&inp[(size_t)(r0 + r) * in_rs + c0 + ch * 4];
  }
  __syncthreads();
  for (int i = 0; i < 4; ++i) {
    int idx = i * 256 + t;
    int r = idx >> 4, ch = idx & 15;
    u16 a0 = tile[ch * 4 + 0][r], a1 = tile[ch * 4 + 1][r];
    u16 a2 = tile[ch * 4 + 2][r], a3 = tile[ch * 4 + 3][r];
    uint2 d;
    d.x = (u32)a0 | ((u32)a1 << 16);
    d.y = (u32)a2 | ((u32)a3 << 16);
    *(uint2*)&outp[(size_t)(c0 + r) * out_rs + r0 + ch * 4] = d;
  }
}

// ---------------- merged Q+K projection GEMM ---------------------------------
// grid (8,16): bx<4 -> Q epilogue (scale+both biases), else K epilogue.
__global__ __launch_bounds__(256) void gemm_qk(
    const float* __restrict__ A, const u16* __restrict__ WqT,
    const u16* __restrict__ WkT, u16* __restrict__ qw, u16* __restrict__ qr,
    u16* __restrict__ Kws, const float* __restrict__ rwb,
    const float* __restrict__ rrb) {
  __shared__ u16 As[128 * 32];
  __shared__ u16 Bs[128 * 32];
  const bool isq = blockIdx.x < 4;
  const u16* BT = isq ? WqT : WkT;
  const int t = threadIdx.x;
  const int lane = t & 63, wid = t >> 6;
  const int l16 = lane & 15, quad = lane >> 4;
  const int wm = wid >> 1, wn = wid & 1;
  const int m0 = blockIdx.y * 128, n0 = (blockIdx.x & 3) * 128;
  const int Kd = CC;

  fx4 acc[4][4] = {};
  for (int k0 = 0; k0 < Kd; k0 += 32) {
    __syncthreads();
    for (int i = 0; i < 2; ++i) {
      int idx = (i * 256 + t) * 8;
      int r = idx >> 5, ko = idx & 31;
      const float* ap = A + (size_t)(m0 + r) * Kd + k0 + ko;
      float4 f0 = *(const float4*)ap;
      float4 f1 = *(const float4*)(ap + 4);
      union { u16 h[8]; uint4 v; } pk;
      pk.h[0] = f2bf(f0.x); pk.h[1] = f2bf(f0.y);
      pk.h[2] = f2bf(f0.z); pk.h[3] = f2bf(f0.w);
      pk.h[4] = f2bf(f1.x); pk.h[5] = f2bf(f1.y);
      pk.h[6] = f2bf(f1.z); pk.h[7] = f2bf(f1.w);
      *(uint4*)&As[r * 32 + ko] = pk.v;
      *(uint4*)&Bs[r * 32 + ko] = *(const uint4*)&BT[(size_t)(n0 + r) * Kd + k0 + ko];
    }
    __syncthreads();
    bf16x8 af[4], bfr[4];
    for (int mi = 0; mi < 4; ++mi)
      af[mi] = *(const bf16x8*)&As[(wm * 64 + mi * 16 + l16) * 32 + quad * 8];
    for (int ni = 0; ni < 4; ++ni)
      bfr[ni] = *(const bf16x8*)&Bs[(wn * 64 + ni * 16 + l16) * 32 + quad * 8];
    for (int mi = 0; mi < 4; ++mi)
      for (int ni = 0; ni < 4; ++ni)
        acc[mi][ni] = mfma16(af[mi], bfr[ni], acc[mi][ni]);
  }

  for (int mi = 0; mi < 4; ++mi)
    for (int ni = 0; ni < 4; ++ni)
      for (int r = 0; r < 4; ++r) {
        int row = m0 + wm * 64 + mi * 16 + quad * 4 + r;
        int col = n0 + wn * 64 + ni * 16 + l16;
        float v = acc[mi][ni][r];
        int h = col >> 6, kx = col & 63;
        size_t o = ((size_t)h * TT + row) * 64 + kx;
        if (isq) {
          float qs = v * 0.125f;
          qw[o] = f2bf(qs + rwb[col]);
          qr[o] = f2bf(qs + rrb[col]);
        } else {
          Kws[o] = f2bf(v);
        }
      }
}

// ---------------- bf16 MFMA GEMM: C = A[M,K] @ BT[N,K]^T ---------------------
// EPI 2: out0 bf16 [m*N+n]=acc     EPI 3: out0 FLOAT [m*N+n]=acc+bias0[n]
template <int EPI, bool AF32>
__global__ __launch_bounds__(256) void gemm_bt(
    const void* __restrict__ A, const u16* __restrict__ BT,
    int M, int N, int Kd,
    void* __restrict__ out0, const float* __restrict__ bias0) {
  __shared__ u16 As[128 * 32];
  __shared__ u16 Bs[128 * 32];
  const int t = threadIdx.x;
  const int lane = t & 63, wid = t >> 6;
  const int l16 = lane & 15, quad = lane >> 4;
  const int wm = wid >> 1, wn = wid & 1;
  const int m0 = blockIdx.y * 128, n0 = blockIdx.x * 128;

  fx4 acc[4][4] = {};
  for (int k0 = 0; k0 < Kd; k0 += 32) {
    __syncthreads();
    for (int i = 0; i < 2; ++i) {
      int idx = (i * 256 + t) * 8;
      int r = idx >> 5, ko = idx & 31;
      if (AF32) {
        const float* ap = (const float*)A + (size_t)(m0 + r) * Kd + k0 + ko;
        float4 f0 = *(const float4*)ap;
        float4 f1 = *(const float4*)(ap + 4);
        union { u16 h[8]; uint4 v; } pk;
        pk.h[0] = f2bf(f0.x); pk.h[1] = f2bf(f0.y);
        pk.h[2] = f2bf(f0.z); pk.h[3] = f2bf(f0.w);
        pk.h[4] = f2bf(f1.x); pk.h[5] = f2bf(f1.y);
        pk.h[6] = f2bf(f1.z); pk.h[7] = f2bf(f1.w);
        *(uint4*)&As[r * 32 + ko] = pk.v;
      } else {
        *(uint4*)&As[r * 32 + ko] =
            *(const uint4*)((const u16*)A + (size_t)(m0 + r) * Kd + k0 + ko);
      }
      *(uint4*)&Bs[r * 32 + ko] = *(const uint4*)&BT[(size_t)(n0 + r) * Kd + k0 + ko];
    }
    __syncthreads();
    bf16x8 af[4], bfr[4];
    for (int mi = 0; mi < 4; ++mi)
      af[mi] = *(const bf16x8*)&As[(wm * 64 + mi * 16 + l16) * 32 + quad * 8];
    for (int ni = 0; ni < 4; ++ni)
      bfr[ni] = *(const bf16x8*)&Bs[(wn * 64 + ni * 16 + l16) * 32 + quad * 8];
    for (int mi = 0; mi < 4; ++mi)
      for (int ni = 0; ni < 4; ++ni)
        acc[mi][ni] = mfma16(af[mi], bfr[ni], acc[mi][ni]);
  }

  for (int mi = 0; mi < 4; ++mi)
    for (int ni = 0; ni < 4; ++ni)
      for (int r = 0; r < 4; ++r) {
        int row = m0 + wm * 64 + mi * 16 + quad * 4 + r;
        int col = n0 + wn * 64 + ni * 16 + l16;
        float v = acc[mi][ni][r];
        if (EPI == 2) {
          ((u16*)out0)[(size_t)row * N + col] = f2bf(v);
        } else {
          ((float*)out0)[(size_t)row * N + col] = v + bias0[col];
        }
      }
}

// ---------------- U/W suffix-sum tables for the rel-position term ------------
__global__ __launch_bounds__(256) void uw_kernel(
    const u16* __restrict__ qr, const float* __restrict__ Wr,
    float* __restrict__ U, float* __restrict__ W) {
  const int h = blockIdx.y;
  const int t = threadIdx.x;
  const int ty = t >> 5, i = t & 31;
  const int q = blockIdx.x * 8 + ty;
  const u16* qp = qr + ((size_t)h * TT + q) * 64;
  const float* wp = Wr + (size_t)i * (HH * KK) + h * 64;
  float s = 0.0f;
  for (int kx = 0; kx < 64; ++kx) s += bf2f(qp[kx]) * wp[kx];
  __shared__ float u[8][33];
  u[ty][i] = s;
  __syncthreads();
  if (i < 16) {
    float su = 0.f, sw = 0.f;
    for (int j = i; j < 16; ++j) { su += u[ty][j]; sw += u[ty][16 + j]; }
    U[((size_t)h * TT + q) * 16 + i] = su;
    W[((size_t)h * TT + q) * 16 + i] = sw;
  }
}

// ---------------- split-K fused flash attention ------------------------------
// 1D grid of 2048 blocks; h = blk&7 (XCD swizzle: one head per XCD),
// ks = (blk>>3)&7, qb = blk>>6. Block = 4 waves, 16 q-rows each.
// Partials: o bf16 (unnormalized), per-row (m, l) f32.
__global__ __launch_bounds__(256) void attn_split(
    const u16* __restrict__ qw, const u16* __restrict__ Kw,
    const u16* __restrict__ vT, const float* __restrict__ Ug,
    const float* __restrict__ Wg, const unsigned char* __restrict__ cidx_g,
    u16* __restrict__ o_part, float* __restrict__ m_part,
    float* __restrict__ l_part) {
  const int blk = blockIdx.x;
  const int h = blk & 7;
  const int ks = (blk >> 3) & 7;
  const int q0 = (blk >> 6) * 64;
  const int t = threadIdx.x;
  const int lane = t & 63, w = t >> 6;
  const int l16 = lane & 15, quad = lane >> 4;

  __shared__ unsigned char cidx[TT];
  __shared__ float Ul[64][17];
  __shared__ float Wl[64][17];
  __shared__ u16 Pl[4][16 * 72];

  *(uint2*)&cidx[t * 8] = *(const uint2*)&cidx_g[t * 8];
  for (int i = t; i < 64 * 16; i += 256) {
    int ql = i >> 4, c = i & 15;
    Ul[ql][c] = Ug[((size_t)h * TT + q0 + ql) * 16 + c];
    Wl[ql][c] = Wg[((size_t)h * TT + q0 + ql) * 16 + c];
  }
  __syncthreads();

  const u16* qp = qw + ((size_t)h * TT + q0 + w * 16 + l16) * 64 + quad * 8;
  const bf16x8 aq0 = *(const bf16x8*)qp;
  const bf16x8 aq1 = *(const bf16x8*)(qp + 32);

  float m_r[4], l_r[4];
  for (int r = 0; r < 4; ++r) { m_r[r] = -3.0e38f; l_r[r] = 0.0f; }
  fx4 o[12] = {};

  const u16* kbase = Kw + (size_t)h * TT * 64;
  const u16* vbase = vT + (size_t)h * VV * TT;
  const int qrl = w * 16 + quad * 4;

  for (int j0 = ks * JBLK; j0 < (ks + 1) * JBLK; j0 += 64) {
    fx4 s[4] = {};
    for (int jt = 0; jt < 4; ++jt) {
      const u16* kp = kbase + (size_t)(j0 + jt * 16 + l16) * 64 + quad * 8;
      s[jt] = mfma16(aq0, *(const bf16x8*)kp, s[jt]);
      s[jt] = mfma16(aq1, *(const bf16x8*)(kp + 32), s[jt]);
    }
    for (int jt = 0; jt < 4; ++jt) {
      int j = j0 + jt * 16 + l16;
      for (int r = 0; r < 4; ++r) {
        int d = j - (q0 + qrl + r);
        int ad = d < 0 ? -d : d;
        int c = cidx[ad];
        float wv = Wl[qrl + r][c];
        s[jt][r] += Ul[qrl + r][c] + (d > 0 ? wv : (d < 0 ? -wv : 0.0f));
      }
    }
    float p[4][4];
    for (int r = 0; r < 4; ++r) {
      float mx = fmaxf(fmaxf(s[0][r], s[1][r]), fmaxf(s[2][r], s[3][r]));
      for (int msk = 1; msk < 16; msk <<= 1) mx = fmaxf(mx, __shfl_xor(mx, msk, 64));
      float mnew = fmaxf(m_r[r], mx);
      float alpha = __expf(m_r[r] - mnew);
      float ps = 0.0f;
      for (int jt = 0; jt < 4; ++jt) { p[jt][r] = __expf(s[jt][r] - mnew); ps += p[jt][r]; }
      for (int msk = 1; msk < 16; msk <<= 1) ps += __shfl_xor(ps, msk, 64);
      l_r[r] = l_r[r] * alpha + ps;
      m_r[r] = mnew;
      for (int vt = 0; vt < 12; ++vt) o[vt][r] *= alpha;
    }
    // P: C-layout -> LDS -> A-layout (wave-private region: wave-local waits)
    asm volatile("s_waitcnt lgkmcnt(0)" ::: "memory");
    for (int jt = 0; jt < 4; ++jt)
      for (int r = 0; r < 4; ++r)
        Pl[w][(quad * 4 + r) * 72 + jt * 16 + l16] = f2bf(p[jt][r]);
    asm volatile("s_waitcnt lgkmcnt(0)" ::: "memory");
    for (int kss = 0; kss < 2; ++kss) {
      bf16x8 pf = *(const bf16x8*)&Pl[w][l16 * 72 + kss * 32 + quad * 8];
      const u16* vp = vbase + (size_t)l16 * TT + j0 + kss * 32 + quad * 8;
      for (int vt = 0; vt < 12; ++vt) {
        bf16x8 bv = *(const bf16x8*)(vp + (size_t)vt * 16 * TT);
        o[vt] = mfma16(pf, bv, o[vt]);
      }
    }
  }
  for (int r = 0; r < 4; ++r) {
    int row = q0 + qrl + r;
    size_t base = ((size_t)(ks * HH + h) * TT + row) * VV;
    for (int vt = 0; vt < 12; ++vt) o_part[base + vt * 16 + l16] = f2bf(o[vt][r]);
    if (l16 == 0) {
      m_part[(size_t)(ks * HH + h) * TT + row] = m_r[r];
      l_part[(size_t)(ks * HH + h) * TT + row] = l_r[r];
    }
  }
}

// ---------------- combine split-K partials -> bf16 aout ----------------------
// grid (T/16, H); block 256 = 16 rows x 16 col-threads (12 channels each)
__global__ __launch_bounds__(256) void attn_combine(
    const u16* __restrict__ o_part, const float* __restrict__ m_part,
    const float* __restrict__ l_part, u16* __restrict__ aout) {
  const int h = blockIdx.y;
  const int row = blockIdx.x * 16 + (threadIdx.x >> 4);
  const int c0 = (threadIdx.x & 15) * 12;

  float m[SPLITS], M = -3.0e38f;
  for (int s = 0; s < SPLITS; ++s) {
    m[s] = m_part[(size_t)(s * HH + h) * TT + row];
    M = fmaxf(M, m[s]);
  }
  float lsum = 0.0f, wgt[SPLITS];
  for (int s = 0; s < SPLITS; ++s) {
    wgt[s] = __expf(m[s] - M);
    lsum += wgt[s] * l_part[(size_t)(s * HH + h) * TT + row];
  }
  float o[12];
  for (int j = 0; j < 12; ++j) o[j] = 0.0f;
  for (int s = 0; s < SPLITS; ++s) {
    const u16* op = o_part + ((size_t)(s * HH + h) * TT + row) * VV + c0;
    float wgts = wgt[s];
    uint2 u0 = *(const uint2*)&op[0];
    uint2 u1 = *(const uint2*)&op[4];
    uint2 u2 = *(const uint2*)&op[8];
    u32 uu[6] = {u0.x, u0.y, u1.x, u1.y, u2.x, u2.y};
    for (int j = 0; j < 6; ++j) {
      o[j * 2 + 0] = fmaf(wgts, bf2f((u16)(uu[j] & 0xFFFF)), o[j * 2 + 0]);
      o[j * 2 + 1] = fmaf(wgts, bf2f((u16)(uu[j] >> 16)), o[j * 2 + 1]);
    }
  }
  float inv = 1.0f / lsum;
  union { u16 hx[12]; uint2 v2[3]; } pk;
  for (int j = 0; j < 12; ++j) pk.hx[j] = f2bf(o[j] * inv);
  u16* dst = aout + (size_t)row * CC + h * VV + c0;
  *(uint2*)&dst[0] = pk.v2[0];
  *(uint2*)&dst[4] = pk.v2[1];
  *(uint2*)&dst[8] = pk.v2[2];
}

extern "C" void kernel_launch(void* const* d_in, const int* in_sizes, int n_in,
                              void* d_out, int out_size, void* d_ws, size_t ws_size,
                              hipStream_t stream) {
  (void)in_sizes; (void)n_in; (void)out_size; (void)ws_size;
  const float* x   = (const float*)d_in[0]; // [2048, 1536]
  const float* Wq  = (const float*)d_in[1]; // [1536, 512]
  const float* Wk  = (const float*)d_in[2]; // [1536, 512]
  const float* Wv  = (const float*)d_in[3]; // [1536, 1536]
  const float* Wr  = (const float*)d_in[4]; // [32, 512]
  const float* rwb = (const float*)d_in[5]; // [512]
  const float* rrb = (const float*)d_in[6]; // [512]
  const float* Wo  = (const float*)d_in[7]; // [1536, 1536]
  const float* bo  = (const float*)d_in[8]; // [1536]

  char* ws = (char*)d_ws;
  size_t off = 0;
  auto alloc = [&](size_t bytes) -> void* {
    void* p = ws + off;
    off += (bytes + 255) & ~(size_t)255;
    return p;
  };
  u16* WqT  = (u16*)alloc((size_t)512 * 1536 * 2);
  u16* WkT  = (u16*)alloc((size_t)512 * 1536 * 2);
  u16* WvT  = (u16*)alloc((size_t)1536 * 1536 * 2);
  u16* WoT  = (u16*)alloc((size_t)1536 * 1536 * 2);
  u16* qw   = (u16*)alloc((size_t)HH * TT * 64 * 2);
  u16* qr   = (u16*)alloc((size_t)HH * TT * 64 * 2);
  u16* Kws  = (u16*)alloc((size_t)HH * TT * 64 * 2);
  u16* vtmp = (u16*)alloc((size_t)TT * CC * 2);
  u16* vTw  = (u16*)alloc((size_t)HH * VV * TT * 2);
  float* Uw = (float*)alloc((size_t)HH * TT * 16 * 4);
  float* Ww = (float*)alloc((size_t)HH * TT * 16 * 4);
  u16* aout = (u16*)alloc((size_t)TT * CC * 2);
  unsigned char* cidx_g = (unsigned char*)alloc(TT);
  u16* o_part   = (u16*)alloc((size_t)SPLITS * HH * TT * VV * 2);
  float* m_part = (float*)alloc((size_t)SPLITS * HH * TT * 4);
  float* l_part = (float*)alloc((size_t)SPLITS * HH * TT * 4);

  // all weight transposes + cidx in one launch
  prep_kernel<<<dim3(24, 24, 5), 256, 0, stream>>>(Wq, Wk, Wv, Wo,
                                                   WqT, WkT, WvT, WoT, cidx_g);

  // Q+K projections (merged), V projection
  gemm_qk<<<dim3(8, 16), 256, 0, stream>>>(x, WqT, WkT, qw, qr, Kws, rwb, rrb);
  gemm_bt<2, true><<<dim3(12, 16), 256, 0, stream>>>(x, WvT, TT, CC, CC, vtmp, nullptr);

  // v -> per-head transposed [h][vv][t]
  transpose_bf16<<<dim3(3, 32, 8), 256, 0, stream>>>(vtmp, vTw, 1536, 2048, 192, (long)192 * 2048);

  // rel-position suffix tables
  uw_kernel<<<dim3(256, 8), 256, 0, stream>>>(qr, Wr, Uw, Ww);

  // split-K fused attention (XCD-swizzled 1D grid) + combine
  attn_split<<<dim3(2048), 256, 0, stream>>>(qw, Kws, vTw, Uw, Ww, cidx_g,
                                             o_part, m_part, l_part);
  attn_combine<<<dim3(128, 8), 256, 0, stream>>>(o_part, m_part, l_part, aout);

  // output projection: bf16 aout @ WoT + bo -> FLOAT d_out
  gemm_bt<3, false><<<dim3(12, 16), 256, 0, stream>>>(aout, WoT, TT, CC, CC, d_out, bo);
}